// Round 1
// baseline (404.075 us; speedup 1.0000x reference)
//
#include <hip/hip_runtime.h>

// GCNConv forward on MI355X.
// N=65536 nodes, E=1048576 edges, D_in=D_out=64.
//
// Pipeline:
//   deg[i]  = 1 + #(dst == i)                 (self-loops folded into init)
//   dinv[i] = rsqrt(deg[i])
//   h       = x @ W                           (fp32, W in LDS)
//   out[i]  = h[i] * dinv[i]^2 + b            (self-loop message + bias)
//   out[dst[e]] += h[src[e]] * dinv[src]*dinv[dst]   (atomic scatter, wave/edge)

__global__ void k_deg_init(unsigned* __restrict__ deg, int n) {
    int i = blockIdx.x * blockDim.x + threadIdx.x;
    if (i < n) deg[i] = 1u;   // self-loop contributes 1 to every node's degree
}

__global__ void k_deg_count(const int* __restrict__ dst, unsigned* __restrict__ deg, int E) {
    int e = blockIdx.x * blockDim.x + threadIdx.x;
    if (e < E) atomicAdd(&deg[dst[e]], 1u);
}

__global__ void k_dinv(const unsigned* __restrict__ deg, float* __restrict__ dinv, int n) {
    int i = blockIdx.x * blockDim.x + threadIdx.x;
    if (i < n) dinv[i] = rsqrtf((float)deg[i]);   // deg >= 1 always
}

// h = x @ W.  One thread per output element; 4 rows per 256-thread block.
// W (64x64 = 16 KB) staged in LDS. Lane c reads sW[k*64+c]: consecutive lanes
// -> consecutive banks, conflict-free. x-row loads are wave-uniform (L1 broadcast).
__global__ void k_gemm(const float* __restrict__ x, const float* __restrict__ W,
                       float* __restrict__ h, int nrows) {
    __shared__ float sW[64 * 64];
    for (int i = threadIdx.x; i < 64 * 64; i += blockDim.x) sW[i] = W[i];
    __syncthreads();
    int row = blockIdx.x * (blockDim.x >> 6) + (threadIdx.x >> 6);
    int c   = threadIdx.x & 63;
    if (row >= nrows) return;
    const float* xr = x + (size_t)row * 64;
    float acc = 0.f;
#pragma unroll
    for (int k = 0; k < 64; ++k) acc = fmaf(xr[k], sW[k * 64 + c], acc);
    h[(size_t)row * 64 + c] = acc;
}

// out = h * dinv^2 + b   (initializes d_out, which the harness poisons to 0xAA)
__global__ void k_init_out(const float* __restrict__ h, const float* __restrict__ dinv,
                           const float* __restrict__ b, float* __restrict__ out, int total) {
    int i = blockIdx.x * blockDim.x + threadIdx.x;
    if (i >= total) return;
    int node = i >> 6, c = i & 63;
    float di = dinv[node];
    out[i] = h[i] * di * di + b[c];
}

// One 64-lane wave per edge; lane = channel. Gather h[src] row (coalesced 256B),
// scale, atomic-scatter into out[dst] row.
__global__ void k_scatter(const int* __restrict__ src, const int* __restrict__ dst,
                          const float* __restrict__ h, const float* __restrict__ dinv,
                          float* __restrict__ out, int E) {
    int e = blockIdx.x * (blockDim.x >> 6) + (threadIdx.x >> 6);
    if (e >= E) return;
    int c = threadIdx.x & 63;
    int s = src[e], d = dst[e];
    float norm = dinv[s] * dinv[d];
    float v = h[(size_t)s * 64 + c] * norm;
    atomicAdd(out + (size_t)d * 64 + c, v);
}

extern "C" void kernel_launch(void* const* d_in, const int* in_sizes, int n_in,
                              void* d_out, int out_size, void* d_ws, size_t ws_size,
                              hipStream_t stream) {
    const float* x  = (const float*)d_in[0];
    const int*   ei = (const int*)d_in[1];   // edge_index, [2, E] flattened
    const float* W  = (const float*)d_in[2];
    const float* b  = (const float*)d_in[3];
    float*       out = (float*)d_out;

    const int N = in_sizes[0] / 64;   // 65536
    const int E = in_sizes[1] / 2;    // 1048576
    const int* src = ei;
    const int* dst = ei + E;

    // Workspace layout: deg (u32 N) | dinv (f32 N) | h (f32 N*64)  ~= 16.8 MB
    unsigned* deg  = (unsigned*)d_ws;
    float*    dinv = (float*)((char*)d_ws + (size_t)N * 4);
    float*    h    = (float*)((char*)d_ws + (size_t)N * 8);

    k_deg_init <<<(N + 255) / 256, 256, 0, stream>>>(deg, N);
    k_deg_count<<<(E + 255) / 256, 256, 0, stream>>>(dst, deg, E);
    k_dinv     <<<(N + 255) / 256, 256, 0, stream>>>(deg, dinv, N);
    k_gemm     <<<(N + 3) / 4, 256, 0, stream>>>(x, W, h, N);
    k_init_out <<<(N * 64 + 255) / 256, 256, 0, stream>>>(h, dinv, b, out, N * 64);
    k_scatter  <<<(E + 3) / 4, 256, 0, stream>>>(src, dst, h, dinv, out, E);
}

// Round 2
// 312.204 us; speedup vs baseline: 1.2943x; 1.2943x over previous
//
#include <hip/hip_runtime.h>

// GCNConv forward on MI355X — CSR pull-aggregation version (no f32 atomics).
// N=65536, E=1048576, D=64.
//
//   deg[i]   = 1 + #(dst==i)                          (self-loop in init)
//   dinv[i]  = rsqrt(deg[i])
//   scan     : row_start = exclusive prefix of (deg-1); cursor = row_start
//   g        = (x @ W) * dinv[row]                    (LDS-tiled fp32 GEMM)
//   binfill  : csr_src[cursor[dst[e]]++] = src[e]     (u32 atomics only)
//   aggregate: out_i = (g_i + sum_{e:dst=i} g_src) * dinv_i + b

#define N_DIM 64

__global__ void k_deg_init(unsigned* __restrict__ deg, int n) {
    int i = blockIdx.x * blockDim.x + threadIdx.x;
    if (i < n) deg[i] = 1u;
}

__global__ void k_deg_count(const int* __restrict__ dst, unsigned* __restrict__ deg, int E) {
    int e = blockIdx.x * blockDim.x + threadIdx.x;
    if (e < E) atomicAdd(&deg[dst[e]], 1u);
}

// Single block of 1024 threads; thread t owns 64 consecutive nodes.
// Produces: dinv, exclusive-prefix row_start (of edge counts = deg-1), cursor.
__global__ void k_scan(const unsigned* __restrict__ deg, float* __restrict__ dinv,
                       unsigned* __restrict__ row_start, unsigned* __restrict__ cursor, int n) {
    __shared__ unsigned sums[1024];
    int t = threadIdx.x;
    int base = t * 64;
    unsigned local[64];
    unsigned s = 0;
#pragma unroll
    for (int j = 0; j < 64; ++j) {
        unsigned d = deg[base + j];
        dinv[base + j] = rsqrtf((float)d);
        local[j] = s;
        s += d - 1u;
    }
    sums[t] = s;
    __syncthreads();
    // Hillis-Steele inclusive scan over 1024 chunk totals.
    for (int off = 1; off < 1024; off <<= 1) {
        unsigned v = (t >= off) ? sums[t - off] : 0u;
        __syncthreads();
        sums[t] += v;
        __syncthreads();
    }
    unsigned chunk_base = (t == 0) ? 0u : sums[t - 1];
#pragma unroll
    for (int j = 0; j < 64; ++j) {
        unsigned v = chunk_base + local[j];
        row_start[base + j] = v;
        cursor[base + j]    = v;
    }
    if (t == 1023) row_start[n] = sums[1023];
}

// g = (x @ W) * dinv[row].  Block = 256 threads, 32 rows per block.
// x tile (32x64) staged in LDS via float4; W transposed into LDS padded
// (stride 65) so per-lane float4 reads are 2-way-bank (free on gfx950).
__global__ void k_gemm_g(const float* __restrict__ x, const float* __restrict__ W,
                         const float* __restrict__ dinv, float* __restrict__ g, int nrows) {
    __shared__ float sX[32 * 64];      // 8 KB
    __shared__ float sWt[64 * 65];     // 16.25 KB, sWt[c*65+k] = W[k][c]
    int tid = threadIdx.x;
    // Stage W transposed.
    for (int idx = tid; idx < 64 * 64; idx += 256) {
        int k = idx >> 6, c = idx & 63;
        sWt[c * 65 + k] = W[k * 64 + c];
    }
    // Stage x tile (512 float4s).
    const float4* x4p = (const float4*)(x + (size_t)blockIdx.x * 32 * 64);
    float4* sX4 = (float4*)sX;
    sX4[tid]       = x4p[tid];
    sX4[tid + 256] = x4p[tid + 256];
    __syncthreads();

    int c  = tid & 63;
    int rg = tid >> 6;             // wave id 0..3, owns rows rg*8 .. rg*8+7
    int row0 = blockIdx.x * 32 + rg * 8;
    float acc[8];
#pragma unroll
    for (int r = 0; r < 8; ++r) acc[r] = 0.f;

    for (int k = 0; k < 64; k += 4) {
        float4 w4 = *(const float4*)&sWt[c * 65 + k];
#pragma unroll
        for (int r = 0; r < 8; ++r) {
            float4 x4 = *(const float4*)&sX[(rg * 8 + r) * 64 + k];  // wave-uniform broadcast
            acc[r] = fmaf(x4.x, w4.x, acc[r]);
            acc[r] = fmaf(x4.y, w4.y, acc[r]);
            acc[r] = fmaf(x4.z, w4.z, acc[r]);
            acc[r] = fmaf(x4.w, w4.w, acc[r]);
        }
    }
#pragma unroll
    for (int r = 0; r < 8; ++r) {
        int row = row0 + r;
        g[(size_t)row * 64 + c] = acc[r] * dinv[row];
    }
}

// Bin edges by dst: u32 atomics on L2-resident cursor, 4B scatter of src ids.
__global__ void k_binfill(const int* __restrict__ src, const int* __restrict__ dst,
                          unsigned* __restrict__ cursor, unsigned* __restrict__ csr_src, int E) {
    int e = blockIdx.x * blockDim.x + threadIdx.x;
    if (e < E) {
        unsigned pos = atomicAdd(&cursor[dst[e]], 1u);
        csr_src[pos] = (unsigned)src[e];
    }
}

// Pull aggregation: one wave per node, lane = channel. After binfill,
// cursor[i] == row_start[i] + count == row end.
__global__ void k_aggregate(const float* __restrict__ g, const unsigned* __restrict__ row_start,
                            const unsigned* __restrict__ row_end, const float* __restrict__ dinv,
                            const unsigned* __restrict__ csr_src, const float* __restrict__ b,
                            float* __restrict__ out, int n) {
    int node = blockIdx.x * 4 + (threadIdx.x >> 6);
    if (node >= n) return;
    int c = threadIdx.x & 63;
    unsigned k  = row_start[node];
    unsigned s1 = row_end[node];
    float acc = g[(size_t)node * 64 + c];     // self-loop term (g = h*dinv)
    for (; k + 4 <= s1; k += 4) {             // 4-deep ILP on the gather chain
        unsigned i0 = csr_src[k], i1 = csr_src[k + 1];
        unsigned i2 = csr_src[k + 2], i3 = csr_src[k + 3];
        float v0 = g[(size_t)i0 * 64 + c];
        float v1 = g[(size_t)i1 * 64 + c];
        float v2 = g[(size_t)i2 * 64 + c];
        float v3 = g[(size_t)i3 * 64 + c];
        acc += v0; acc += v1; acc += v2; acc += v3;
    }
    for (; k < s1; ++k) acc += g[(size_t)csr_src[k] * 64 + c];
    out[(size_t)node * 64 + c] = acc * dinv[node] + b[c];
}

extern "C" void kernel_launch(void* const* d_in, const int* in_sizes, int n_in,
                              void* d_out, int out_size, void* d_ws, size_t ws_size,
                              hipStream_t stream) {
    const float* x  = (const float*)d_in[0];
    const int*   ei = (const int*)d_in[1];
    const float* W  = (const float*)d_in[2];
    const float* b  = (const float*)d_in[3];
    float*       out = (float*)d_out;

    const int N = in_sizes[0] / N_DIM;   // 65536
    const int E = in_sizes[1] / 2;       // 1048576
    const int* src = ei;
    const int* dst = ei + E;

    // Workspace layout (offsets in bytes, all 512-aligned):
    //   deg       u32[N]      @ 0
    //   dinv      f32[N]      @ 1*N*4
    //   row_start u32[N+1]    @ 2*N*4
    //   cursor    u32[N]      @ 3*N*4 + 512
    //   csr_src   u32[E]      @ 4*N*4 + 1024
    //   g         f32[N*64]   @ 4*N*4 + E*4 + 1536       (~21.3 MB total)
    char* ws = (char*)d_ws;
    unsigned* deg       = (unsigned*)(ws);
    float*    dinv      = (float*)   (ws + (size_t)N * 4);
    unsigned* row_start = (unsigned*)(ws + (size_t)N * 8);
    unsigned* cursor    = (unsigned*)(ws + (size_t)N * 12 + 512);
    unsigned* csr_src   = (unsigned*)(ws + (size_t)N * 16 + 1024);
    float*    g         = (float*)   (ws + (size_t)N * 16 + (size_t)E * 4 + 1536);

    k_deg_init <<<(N + 255) / 256, 256, 0, stream>>>(deg, N);
    k_deg_count<<<(E + 255) / 256, 256, 0, stream>>>(dst, deg, E);
    k_scan     <<<1, 1024, 0, stream>>>(deg, dinv, row_start, cursor, N);
    k_gemm_g   <<<N / 32, 256, 0, stream>>>(x, W, dinv, g, N);
    k_binfill  <<<(E + 255) / 256, 256, 0, stream>>>(src, dst, cursor, csr_src, E);
    k_aggregate<<<(N + 3) / 4, 256, 0, stream>>>(g, row_start, cursor, dinv, csr_src, b, out, N);
}